// Round 3
// baseline (556.389 us; speedup 1.0000x reference)
//
#include <hip/hip_runtime.h>

#define N_HITS 8192
#define E_MAX  8192
#define NSTA   32
#define NTRK   1024
#define NCHUNK 128   // N_HITS / 64

// ---- workspace layout (bytes) ----
#define WS_HITA    0         // float4[8192]  (phin, zn, ev, st)
#define WS_HTRACK  131072    // float [8192]
#define WS_CAND    163840    // float4[8192]  (phin, zn, ev, track) sorted by station
#define WS_CCNT    294912    // int[32*128]   station chunk counts
#define WS_COFF    311296    // int[32*128]
#define WS_BSTART  327680    // int[33] (padded to 256B)
#define WS_RCNT    327936    // int[8192]
#define WS_ROFF    360704    // int[8192]
#define WS_TCNT    393472    // int[1024]  track counts   (memset 0)
#define WS_TFILL   397568    // int[1024]  track fill pos (memset 0)
#define WS_TOFF    401664    // int[1024]  track offsets
#define WS_THITS   405760    // int[8192]  hits grouped by track

// ---- output layout (float elements) ----
#define OFF_X  0
#define OFF_RI 24576
#define OFF_RO 67133440
#define OFF_Y  134242304
#define OFF_E  134250496
#define OFF_M  134266880

// K1: normalize + X write + packed hit data + station chunk-histogram + track histogram
__global__ void k_pre(const float* __restrict__ ed, float* __restrict__ out,
                      float4* __restrict__ hitA, float* __restrict__ htrack,
                      int* __restrict__ ccnt, int* __restrict__ tcnt) {
    int h = blockIdx.x * blockDim.x + threadIdx.x;   // grid exactly 8192
    int lane = threadIdx.x & 63;
    int w = h >> 6;                                   // global wave/chunk id
    const float* row = ed + h * 6;
    float ev = row[0], x = row[1], y = row[2], z = row[3], stf = row[4], tr = row[5];
    float r   = sqrtf(x * x + y * y);
    float phi = atan2f(x, y);                         // jnp.arctan2(x, y)
    float rn   = 2.0f * (r   - 269.0f)  / 312.0f  - 1.0f;
    float phin = 2.0f * (phi + 3.15f)   / 6.3f    - 1.0f;
    float zn   = 2.0f * (z   + 2386.0f) / 4772.0f - 1.0f;
    out[OFF_X + h * 3 + 0] = rn;
    out[OFF_X + h * 3 + 1] = phin;
    out[OFF_X + h * 3 + 2] = zn;
    int st = (int)stf;
    hitA[h] = make_float4(phin, zn, (float)(int)ev, stf);
    htrack[h] = tr;
    for (int b = 0; b < NSTA; ++b) {
        unsigned long long m = __ballot(st == b);
        if (lane == 0) ccnt[b * NCHUNK + w] = __popcll(m);
    }
    atomicAdd(&tcnt[(int)tr], 1);
}

// K2: scan station chunk counts (bucket-major) -> coff, bstart; scan track counts -> toff
__global__ void k_scans(const int* __restrict__ ccnt, int* __restrict__ coff,
                        int* __restrict__ bstart,
                        const int* __restrict__ tcnt, int* __restrict__ toff) {
    __shared__ int sums[256];
    int tid = threadIdx.x;
    // phase A: 4096 station-chunk counts, 16 per thread
    {
        int base = tid * 16;
        int loc[16]; int s = 0;
        for (int k = 0; k < 16; ++k) { loc[k] = ccnt[base + k]; s += loc[k]; }
        sums[tid] = s; __syncthreads();
        for (int d = 1; d < 256; d <<= 1) {
            int v = (tid >= d) ? sums[tid - d] : 0;
            __syncthreads();
            sums[tid] += v;
            __syncthreads();
        }
        int run = sums[tid] - s;
        for (int k = 0; k < 16; ++k) { coff[base + k] = run; run += loc[k]; }
        __syncthreads();
        if (tid < NSTA) bstart[tid] = coff[tid * NCHUNK];
        if (tid == 0)   bstart[NSTA] = N_HITS;
        __syncthreads();
    }
    // phase B: 1024 track counts, 4 per thread
    {
        int base = tid * 4;
        int loc[4]; int s = 0;
        for (int k = 0; k < 4; ++k) { loc[k] = tcnt[base + k]; s += loc[k]; }
        sums[tid] = s; __syncthreads();
        for (int d = 1; d < 256; d <<= 1) {
            int v = (tid >= d) ? sums[tid - d] : 0;
            __syncthreads();
            sums[tid] += v;
            __syncthreads();
        }
        int run = sums[tid] - s;
        for (int k = 0; k < 4; ++k) { toff[base + k] = run; run += loc[k]; }
    }
}

// K3: stable station scatter -> cand; track scatter -> thits (order in bucket irrelevant)
__global__ void k_scatter(const float4* __restrict__ hitA, const float* __restrict__ htrack,
                          const int* __restrict__ coff, float4* __restrict__ cand,
                          const int* __restrict__ toff, int* __restrict__ tfill,
                          int* __restrict__ thits) {
    int h = blockIdx.x * blockDim.x + threadIdx.x;
    int lane = threadIdx.x & 63;
    int w = h >> 6;
    float4 a = hitA[h];
    float tr = htrack[h];
    int st = (int)a.w;
    for (int b = 0; b < NSTA; ++b) {
        unsigned long long m = __ballot(st == b);
        if (st == b) {
            int rank = __popcll(m & ((1ull << lane) - 1ull));
            cand[coff[b * NCHUNK + w] + rank] = make_float4(a.x, a.y, a.z, tr);
        }
    }
    int ti = (int)tr;
    int pos = atomicAdd(&tfill[ti], 1);
    thits[toff[ti] + pos] = h;
}

__device__ __forceinline__ bool edge_pred(float4 me, float4 cj) {
    float dphi = cj.x - me.x;
    float dz   = cj.y - me.y;
    return (cj.z == me.z) & (dphi > -0.04f) & (dphi < 0.04f)
                          & (dz > -0.03f) & (dz < 0.03f);
}

// K4: per-row edge count (one wave per row)
__global__ void k_rowcount(const float4* __restrict__ hitA, const float4* __restrict__ cand,
                           const int* __restrict__ bstart, int* __restrict__ rcnt) {
    int tid = threadIdx.x;
    int lane = tid & 63;
    int row = blockIdx.x * (blockDim.x >> 6) + (tid >> 6);
    float4 me = hitA[row];
    int b = (int)me.w + 1;
    int cnt = 0;
    if (b >= 1 && b < NSTA) {
        int s = bstart[b], e = bstart[b + 1];
        for (int k0 = s; k0 < e; k0 += 64) {
            int kk = k0 + lane;
            bool p = false;
            if (kk < e) p = edge_pred(me, cand[kk]);
            cnt += __popcll(__ballot(p));
        }
    }
    if (lane == 0) rcnt[row] = cnt;
}

// K5: scan row counts -> roff; then edge_mask + pad edges with track[0]
__global__ void k_scanrows(const int* __restrict__ rcnt, int* __restrict__ roff,
                           const float* __restrict__ htrack, float* __restrict__ out) {
    __shared__ int sums[256];
    int tid = threadIdx.x;
    int base = tid * 32;
    int loc[32]; int s = 0;
    for (int k = 0; k < 32; ++k) { loc[k] = rcnt[base + k]; s += loc[k]; }
    sums[tid] = s; __syncthreads();
    for (int d = 1; d < 256; d <<= 1) {
        int v = (tid >= d) ? sums[tid - d] : 0;
        __syncthreads();
        sums[tid] += v;
        __syncthreads();
    }
    int run = sums[tid] - s;
    for (int k = 0; k < 32; ++k) { roff[base + k] = run; run += loc[k]; }
    __syncthreads();
    int S = sums[255];               // total valid edges (may exceed E_MAX)
    float t0 = htrack[0];
    for (int e = tid; e < E_MAX; e += 256) {
        bool v = e < S;
        out[OFF_M + e] = v ? 1.0f : 0.0f;
        if (!v) {                    // nonzero fill_value=0 -> hit 0's track
            out[OFF_E + 2 * e]     = t0;
            out[OFF_E + 2 * e + 1] = t0;
        }
    }
}

// K6: ordered edge emission + sparse Ri/Ro ones via track CSR
__global__ void k_emit(const float4* __restrict__ hitA, const float* __restrict__ htrack,
                       const float4* __restrict__ cand, const int* __restrict__ bstart,
                       const int* __restrict__ roff, const int* __restrict__ toff,
                       const int* __restrict__ tcnt, const int* __restrict__ thits,
                       float* __restrict__ out) {
    int tid = threadIdx.x;
    int lane = tid & 63;
    int row = blockIdx.x * (blockDim.x >> 6) + (tid >> 6);
    float4 me = hitA[row];
    int b = (int)me.w + 1;
    if (b < 1 || b >= NSTA) return;   // wave-uniform
    float tr_i = htrack[row];
    int bo = (int)tr_i;               // src-track bucket (same for whole row)
    int os = toff[bo], oc = tcnt[bo];
    int s = bstart[b], e = bstart[b + 1];
    int base = roff[row];
    int c = 0;
    for (int k0 = s; k0 < e; k0 += 64) {
        int kk = k0 + lane;
        float4 cj = make_float4(0.f, 0.f, 0.f, 0.f);
        bool p = false;
        if (kk < e) { cj = cand[kk]; p = edge_pred(me, cj); }
        unsigned long long m = __ballot(p);
        if (p) {
            int idx = base + c + __popcll(m & ((1ull << lane) - 1ull));
            if (idx < E_MAX) {
                out[OFF_E + 2 * idx]     = tr_i;   // edges[:,0] = src track
                out[OFF_E + 2 * idx + 1] = cj.w;   // edges[:,1] = dst track
                // Ro[h, idx] = 1 for hits h with track == src track
                for (int j = 0; j < oc; ++j)
                    out[OFF_RO + (size_t)thits[os + j] * E_MAX + idx] = 1.0f;
                // Ri[h, idx] = 1 for hits h with track == dst track
                int bi = (int)cj.w;
                int is = toff[bi], ic = tcnt[bi];
                for (int j = 0; j < ic; ++j)
                    out[OFF_RI + (size_t)thits[is + j] * E_MAX + idx] = 1.0f;
            }
        }
        c += __popcll(m);
    }
}

extern "C" void kernel_launch(void* const* d_in, const int* in_sizes, int n_in,
                              void* d_out, int out_size, void* d_ws, size_t ws_size,
                              hipStream_t stream) {
    const float* ed = (const float*)d_in[0];
    float* out = (float*)d_out;
    char* ws = (char*)d_ws;

    float4* hitA   = (float4*)(ws + WS_HITA);
    float*  htrack = (float*) (ws + WS_HTRACK);
    float4* cand   = (float4*)(ws + WS_CAND);
    int*    ccnt   = (int*)   (ws + WS_CCNT);
    int*    coff   = (int*)   (ws + WS_COFF);
    int*    bstart = (int*)   (ws + WS_BSTART);
    int*    rcnt   = (int*)   (ws + WS_RCNT);
    int*    roffp  = (int*)   (ws + WS_ROFF);
    int*    tcnt   = (int*)   (ws + WS_TCNT);
    int*    tfill  = (int*)   (ws + WS_TFILL);
    int*    toff   = (int*)   (ws + WS_TOFF);
    int*    thits  = (int*)   (ws + WS_THITS);

    // zero Ri + Ro + y_lbl (536.9 MB) via the runtime's tuned fill path
    hipMemsetAsync(out + OFF_RI, 0, (size_t)(OFF_E - OFF_RI) * sizeof(float), stream);
    // zero track histogram + fill counters (8 KB)
    hipMemsetAsync(ws + WS_TCNT, 0, 2 * NTRK * sizeof(int), stream);

    hipLaunchKernelGGL(k_pre,      dim3(32),   dim3(256), 0, stream, ed, out, hitA, htrack, ccnt, tcnt);
    hipLaunchKernelGGL(k_scans,    dim3(1),    dim3(256), 0, stream, ccnt, coff, bstart, tcnt, toff);
    hipLaunchKernelGGL(k_scatter,  dim3(32),   dim3(256), 0, stream, hitA, htrack, coff, cand, toff, tfill, thits);
    hipLaunchKernelGGL(k_rowcount, dim3(2048), dim3(256), 0, stream, hitA, cand, bstart, rcnt);
    hipLaunchKernelGGL(k_scanrows, dim3(1),    dim3(256), 0, stream, rcnt, roffp, htrack, out);
    hipLaunchKernelGGL(k_emit,     dim3(2048), dim3(256), 0, stream, hitA, htrack, cand, bstart, roffp, toff, tcnt, thits, out);
}